// Round 9
// baseline (90.789 us; speedup 1.0000x reference)
//
#include <hip/hip_runtime.h>
#include <math.h>

#define B_  4
#define P_  512
#define K_  4
#define H_  200
#define W_  336
#define A_  14
#define PS_ 56
#define SCALE_ 0.25f
#define HW_    (H_ * W_)
#define ROWB_  (W_ * 8)          // bytes per row of [W][K] bf16 (2688)
#define PLB_   (HW_ * 8)         // bytes per (b) plane (2.15 MB total)
#define RROWB_ (PS_ * K_ * 4)    // bytes per smR row (= 896)

#if __has_builtin(__builtin_amdgcn_exp2f)
#define EXP2F(x) __builtin_amdgcn_exp2f(x)
#else
#define EXP2F(x) exp2f(x)
#endif

// bf16 round-to-nearest-even
static __device__ __forceinline__ unsigned f2bf(float x) {
    unsigned u = __float_as_uint(x);
    return (u + 0x7fffu + ((u >> 16) & 1u)) >> 16;
}
static __device__ __forceinline__ unsigned pk2(float a, float b) {
    return f2bf(a) | (f2bf(b) << 16);
}
#define LOF(u) __uint_as_float((u) << 16)
#define HIF(u) __uint_as_float((u) & 0xffff0000u)

// 16B load at 8B-aligned address
static __device__ __forceinline__ uint4 ld16u8(const char* p) {
    uint4 q;
    __builtin_memcpy(&q, (const char*)__builtin_assume_aligned(p, 8), 16);
    return q;
}

// ---- Pass 1: bases [B,K,H,W] -> ws [B,H,W] = bf16 {k0|k1, k2|k3} (8B/pixel) ----
__global__ __launch_bounds__(256) void transpose_bases(
    const float* __restrict__ bases, unsigned long long* __restrict__ ws)
{
    const int i = blockIdx.x * 256 + threadIdx.x;    // over B*H*W = 268800
    if (i >= B_ * HW_) return;
    const int b = i / HW_;
    const int r = i - b * HW_;
    const float* src = bases + (size_t)b * (K_ * HW_) + r;
    const unsigned lo = pk2(src[0 * HW_], src[1 * HW_]);
    const unsigned hi = pk2(src[2 * HW_], src[3 * HW_]);
    const unsigned long long w = (unsigned long long)lo
                               | ((unsigned long long)hi << 32);
    __builtin_nontemporal_store(w, ws + i);
}

// ---- Pass 2: main blender, 2 proposals per block (same b) ----
__global__ __launch_bounds__(448) void blender_kernel(
    const unsigned long long* __restrict__ wsb,  // [B,H,W,K] bf16-packed bases
    const float* __restrict__ boxes,   // [B,P,4]
    const float* __restrict__ attn,    // [B,P,K,A,A]
    float* __restrict__ out)           // [B,P,PS,PS]
{
    const int tid = threadIdx.x;       // 448 threads, 7 waves
    const int bp0 = blockIdx.x * 2;    // first of 2 proposals
    const int b   = bp0 >> 9;          // / 512 (both proposals share b)

    __shared__ float  smTile[2 * K_ * A_ * A_];   // raw attn tiles (1568 f)
    __shared__ float  smR[2 * A_ * PS_ * K_];     // x-interp attn*log2e (6272 f)
    __shared__ float4 smX[2 * PS_];               // {asint(x0*8), wl, wh, -}
    __shared__ float4 smY[2 * PS_];               // {asint(y0*ROWB), asint(dy*ROWB), wy0, wy1}
    __shared__ float2 smAY[2 * PS_];              // {asint(iy0*RROWB_), ty}

    // ---- stage both attn tiles ----
    const float* ap = attn + (size_t)bp0 * (K_ * A_ * A_);
    for (int i = tid; i < 2 * K_ * A_ * A_; i += 448)
        smTile[i] = __builtin_nontemporal_load(ap + i);

    // ---- separable tables (q = proposal within block) ----
    const float rr = 13.0f / 55.0f;               // (A-1)/(PS-1)

    if (tid < 112) {                              // x-side
        const int q  = tid / PS_;
        const int px = tid - q * PS_;
        const float* bx = boxes + (size_t)(bp0 + q) * 4;
        const float x1 = bx[0] * SCALE_;
        const float x2 = bx[2] * SCALE_;
        const float bw = fmaxf(x2 - x1, 1.0f) * (1.0f / PS_);
        const float sx = x1 + (px + 0.5f) * bw;
        const float vx = (sx > -1.0f && sx < (float)W_) ? 1.0f : 0.0f;
        const float cx = fminf(fmaxf(sx, 0.0f), (float)(W_ - 1));
        const int   x0 = (int)cx;
        const float lx = cx - (float)x0;          // x0==W-1 -> lx==0 -> hi*0
        float4 v;
        v.x = __int_as_float(x0 * 8);
        v.y = (1.0f - lx) * vx;
        v.z = lx * vx;
        v.w = 0.0f;
        smX[tid] = v;
    } else if (tid >= 128 && tid < 240) {         // y-side
        const int t2 = tid - 128;
        const int q  = t2 / PS_;
        const int py = t2 - q * PS_;
        const float* bx = boxes + (size_t)(bp0 + q) * 4;
        const float y1 = bx[1] * SCALE_;
        const float y2 = bx[3] * SCALE_;
        const float bh = fmaxf(y2 - y1, 1.0f) * (1.0f / PS_);
        const float sy = y1 + (py + 0.5f) * bh;
        const float vy = (sy > -1.0f && sy < (float)H_) ? 1.0f : 0.0f;
        const float cy = fminf(fmaxf(sy, 0.0f), (float)(H_ - 1));
        const int   y0 = (int)cy;
        const int   y1i = min(y0 + 1, H_ - 1);
        const float ly = cy - (float)y0;
        float4 v;
        v.x = __int_as_float(y0 * ROWB_);
        v.y = __int_as_float((y1i - y0) * ROWB_);
        v.z = (1.0f - ly) * vy;
        v.w = ly * vy;
        smY[t2] = v;
        const float srcy = (float)py * rr;
        const int iy0 = min((int)srcy, A_ - 2);
        float2 a;
        a.x = __int_as_float(iy0 * RROWB_);
        a.y = srcy - (float)iy0;
        smAY[t2] = a;
    }
    __syncthreads();

    // ---- x-interp attn -> smR[q][ay][px][k], pre-scaled by log2(e) ----
    const float LOG2E = 1.4426950408889634f;
    for (int i = tid; i < 2 * K_ * A_ * PS_; i += 448) {
        const int q  = i / (K_ * A_ * PS_);
        const int j  = i - q * (K_ * A_ * PS_);
        const int k  = j / (A_ * PS_);
        const int r1 = j - k * (A_ * PS_);
        const int ay = r1 / PS_;
        const int px = r1 - ay * PS_;
        const float srcx = (float)px * rr;
        const int ix0 = min((int)srcx, A_ - 2);
        const float tx = srcx - (float)ix0;
        const float* t = smTile + q * (K_ * A_ * A_) + k * (A_ * A_) + ay * A_ + ix0;
        smR[q * (A_ * PS_ * K_) + (ay * PS_ + px) * K_ + k] =
            (t[0] + tx * (t[1] - t[0])) * LOG2E;
    }
    __syncthreads();

    // ---- main loop: fixed (q, px, py0); 14 rows per thread; 2-slot pipeline ----
    const char* fb = (const char*)wsb + (size_t)b * PLB_;

    const int qq  = tid / 224;                    // proposal
    const int u   = tid - qq * 224;
    const int px  = u % PS_;
    const int py0 = u / PS_;                      // 0..3

    const float4 X = smX[qq * PS_ + px];          // once per thread
    const unsigned xb = (unsigned)__float_as_int(X.x);
    const float wl = X.y, wh = X.z;
    const char* smRbase = (const char*)(smR + qq * (A_ * PS_ * K_)) + (px << 4);
    float* outq = out + (size_t)(bp0 + qq) * (PS_ * PS_) + py0 * PS_ + px;
    const float4* smYq  = smY  + qq * PS_;
    const float2* smAYq = smAY + qq * PS_;

    struct PState {
        uint4 r0, r1;
        float wy0, wy1, ty;
        int   ayo;
    };

    auto issue = [&](int t, PState& S) {
        const int py = py0 + 4 * t;
        const float4 Y  = smYq[py];
        const float2 AY = smAYq[py];
        const unsigned o0 = (unsigned)__float_as_int(Y.x) + xb;
        const unsigned o1 = o0 + (unsigned)__float_as_int(Y.y);
        S.r0 = ld16u8(fb + o0);                   // (y0, x0 & x0+1, k0..3) bf16
        S.r1 = ld16u8(fb + o1);                   // (y1, ...)
        S.wy0 = Y.z; S.wy1 = Y.w;
        S.ty = AY.y; S.ayo = __float_as_int(AY.x);
    };

    auto compute = [&](const PState& S) -> float {
        const float wy0 = S.wy0, wy1 = S.wy1, ty = S.ty;
        const float r0a = fmaf(LOF(S.r0.z), wh, LOF(S.r0.x) * wl);
        const float r0b = fmaf(HIF(S.r0.z), wh, HIF(S.r0.x) * wl);
        const float r0c = fmaf(LOF(S.r0.w), wh, LOF(S.r0.y) * wl);
        const float r0d = fmaf(HIF(S.r0.w), wh, HIF(S.r0.y) * wl);
        const float r1a = fmaf(LOF(S.r1.z), wh, LOF(S.r1.x) * wl);
        const float r1b = fmaf(HIF(S.r1.z), wh, HIF(S.r1.x) * wl);
        const float r1c = fmaf(LOF(S.r1.w), wh, LOF(S.r1.y) * wl);
        const float r1d = fmaf(HIF(S.r1.w), wh, HIF(S.r1.y) * wl);
        const float v0 = fmaf(r1a, wy1, r0a * wy0);
        const float v1 = fmaf(r1b, wy1, r0b * wy0);
        const float v2 = fmaf(r1c, wy1, r0c * wy0);
        const float v3 = fmaf(r1d, wy1, r0d * wy0);

        const float4 a0v = *(const float4*)(smRbase + S.ayo);
        const float4 a1v = *(const float4*)(smRbase + S.ayo + RROWB_);
        const float e0 = EXP2F(fmaf(ty, a1v.x - a0v.x, a0v.x));
        const float e1 = EXP2F(fmaf(ty, a1v.y - a0v.y, a0v.y));
        const float e2 = EXP2F(fmaf(ty, a1v.z - a0v.z, a0v.z));
        const float e3 = EXP2F(fmaf(ty, a1v.w - a0v.w, a0v.w));

        const float s = (e0 + e1) + (e2 + e3);
        float acc = e0 * v0;
        acc = fmaf(e1, v1, acc);
        acc = fmaf(e2, v2, acc);
        acc = fmaf(e3, v3, acc);
        return acc * __builtin_amdgcn_rcpf(s);
    };

    PState SA, SB;
    issue(0, SA);
    issue(1, SB);
    #pragma unroll
    for (int t = 0; t < 12; t += 2) {
        __builtin_nontemporal_store(compute(SA), outq + t * (4 * PS_));
        issue(t + 2, SA);
        __builtin_nontemporal_store(compute(SB), outq + (t + 1) * (4 * PS_));
        issue(t + 3, SB);
    }
    __builtin_nontemporal_store(compute(SA), outq + 12 * (4 * PS_));
    __builtin_nontemporal_store(compute(SB), outq + 13 * (4 * PS_));
}

extern "C" void kernel_launch(void* const* d_in, const int* in_sizes, int n_in,
                              void* d_out, int out_size, void* d_ws, size_t ws_size,
                              hipStream_t stream) {
    const float* bases = (const float*)d_in[0];  // [B,K,H,W]
    const float* boxes = (const float*)d_in[1];  // [B,P,4]
    const float* attn  = (const float*)d_in[2];  // [B,P,K,A,A]
    float* out = (float*)d_out;                  // [B,P,PS,PS]
    unsigned long long* wsb = (unsigned long long*)d_ws;  // 268800 * 8 B = 2.15 MB

    transpose_bases<<<dim3((B_ * HW_ + 255) / 256), dim3(256), 0, stream>>>(bases, wsb);
    blender_kernel<<<dim3(B_ * P_ / 2), dim3(448), 0, stream>>>(wsb, boxes, attn, out);
}